// Round 4
// baseline (2003.750 us; speedup 1.0000x reference)
//
#include <hip/hip_runtime.h>

#define NN 100000
#define LN_EPS 1e-5f

typedef unsigned int uint_t;
typedef unsigned short ushort_t;
typedef __attribute__((ext_vector_type(8))) short short8v;
typedef __attribute__((ext_vector_type(4))) float f32x4;

// round-to-nearest-even f32 -> bf16
__device__ __forceinline__ ushort_t bf16_rte(float x) {
  uint_t u = __float_as_uint(x);
  u = (u + 0x7FFFu + ((u >> 16) & 1u)) >> 16;
  return (ushort_t)u;
}
__device__ __forceinline__ uint_t pack_bf16x2(float a, float b) {
  uint_t ua = __float_as_uint(a);
  ua = (ua + 0x7FFFu + ((ua >> 16) & 1u)) >> 16;
  uint_t ub = __float_as_uint(b);
  ub = (ub + 0x7FFFu + ((ub >> 16) & 1u)) & 0xFFFF0000u;
  return ua | ub;
}
__device__ __forceinline__ float bf_lo(uint_t u) { return __uint_as_float(u << 16); }
__device__ __forceinline__ float bf_hi(uint_t u) { return __uint_as_float(u & 0xFFFF0000u); }

// ---------------- CSR build ----------------

__global__ void k_hist(const int* __restrict__ dst, int* __restrict__ deg, int E) {
  int i = blockIdx.x * 256 + threadIdx.x;
  if (i < E) atomicAdd(&deg[dst[i]], 1);
}

__global__ void k_dis(const int* __restrict__ deg, float* __restrict__ dis, int n) {
  int i = blockIdx.x * 256 + threadIdx.x;
  if (i < n) dis[i] = rsqrtf((float)(deg[i] + 1));   // +1 self loop
}

// block scans 2048 elements (8 per thread)
__global__ void k_scanA(const int* __restrict__ deg, int* __restrict__ rp,
                        int* __restrict__ bsum, int n) {
  __shared__ int sh[256];
  int t = threadIdx.x;
  int base = blockIdx.x * 2048 + t * 8;
  int v[8];
  int s = 0;
#pragma unroll
  for (int i = 0; i < 8; ++i) {
    int idx = base + i;
    v[i] = (idx < n) ? deg[idx] : 0;
    s += v[i];
  }
  sh[t] = s;
  __syncthreads();
  for (int d = 1; d < 256; d <<= 1) {
    int add = (t >= d) ? sh[t - d] : 0;
    __syncthreads();
    sh[t] += add;
    __syncthreads();
  }
  int excl = sh[t] - s;
  if (t == 255) bsum[blockIdx.x] = sh[255];
  int run = excl;
#pragma unroll
  for (int i = 0; i < 8; ++i) {
    int idx = base + i;
    if (idx < n) rp[idx] = run;
    run += v[i];
  }
}

__global__ void k_scanB(int* bsum, int nb) {
  int t = threadIdx.x;
  int x = (t < nb) ? bsum[t] : 0;
  int incl = x;
#pragma unroll
  for (int d = 1; d < 64; d <<= 1) {
    int y = __shfl_up(incl, d, 64);
    if (t >= d) incl += y;
  }
  if (t < nb) bsum[t] = incl - x;
}

__global__ void k_scanC(int* __restrict__ rp, const int* __restrict__ bsum, int n, int total) {
  int i = blockIdx.x * 256 + threadIdx.x;
  if (i < n) rp[i] += bsum[i >> 11];
  else if (i == n) rp[n] = total;
}

// bucket scatter: bucket b = dst>>8 owns csr range [rp[b*256], ...). Appends are
// monotonic per bucket -> ~391 active cache lines, L2-hot, writeback ~= data.
__global__ void k_bscatter(const int* __restrict__ src, const int* __restrict__ dst,
                           const int* __restrict__ rp, int* __restrict__ bfill,
                           int2* __restrict__ pairs, int E) {
  int i = blockIdx.x * 256 + threadIdx.x;
  if (i < E) {
    int d = dst[i], s = src[i];
    int b = d >> 8;
    int pos = rp[b << 8] + atomicAdd(&bfill[b], 1);
    pairs[pos] = make_int2(s, d);
  }
}

// final fill: a block's pair chunk spans ~1 bucket (256 nodes) -> csrc writes land
// in a ~16KB window, fill[] atomics on ~1KB of counters.
__global__ void k_fill2(const int2* __restrict__ pairs, const int* __restrict__ rp,
                        int* __restrict__ fill, int* __restrict__ csrc, int E) {
  int i = blockIdx.x * 256 + threadIdx.x;
  if (i < E) {
    int2 p = pairs[i];
    int pos = rp[p.y] + atomicAdd(&fill[p.y], 1);
    csrc[pos] = p.x;
  }
}

// ---------------- fp32 -> bf16 convert (encoder input) ----------------

__global__ void k_cvt(const float* __restrict__ x, ushort_t* __restrict__ y, int total4) {
  int i = blockIdx.x * 256 + threadIdx.x;
  if (i < total4) {
    float4 v = *(const float4*)&x[i * 4];
    uint2 p;
    p.x = pack_bf16x2(v.x, v.y);
    p.y = pack_bf16x2(v.z, v.w);
    *(uint2*)&y[i * 4] = p;
  }
}

// ---------------- W pack: fp32 [K][128] -> bf16 MFMA B-frag order ----------------
// t in [0, KK*512): lane holds B[k=(t>>9)*32+((t&63)>>4)*8+i][col=((t>>6)&7)*16+(t&15)]

__global__ void k_packw(const float* __restrict__ W, ushort_t* __restrict__ P) {
  int t = blockIdx.x * 256 + threadIdx.x;
  int lane = t & 63;
  int j = (t >> 6) & 7;
  int kk = t >> 9;
  int krow = kk * 32 + (lane >> 4) * 8;
  int col = j * 16 + (lane & 15);
  ushort_t o[8];
#pragma unroll
  for (int i = 0; i < 8; ++i) o[i] = bf16_rte(W[(size_t)(krow + i) * 128 + col]);
  uint4 v;
  v.x = (uint_t)o[0] | ((uint_t)o[1] << 16);
  v.y = (uint_t)o[2] | ((uint_t)o[3] << 16);
  v.z = (uint_t)o[4] | ((uint_t)o[5] << 16);
  v.w = (uint_t)o[6] | ((uint_t)o[7] << 16);
  *(uint4*)&P[(size_t)t * 8] = v;
}

// ---------------- bf16 MFMA GEMM ----------------
// KK = K/32. ENC: epilogue = relu(acc + bias[col]); else: acc * dis[row].
// A: [n][KK*32] bf16 row-major. One wave per 16 rows, LDS-free.

template <int KK, bool ENC>
__global__ __launch_bounds__(256) void k_gemm_mfma(const ushort_t* __restrict__ A,
                                                   const ushort_t* __restrict__ Wp,
                                                   const float* __restrict__ aux,
                                                   ushort_t* __restrict__ C, int n) {
  int lane = threadIdx.x & 63;
  int wid = threadIdx.x >> 6;
  int r0 = (blockIdx.x * 4 + wid) * 16;
  if (r0 >= n) return;
  int arow = r0 + (lane & 15);
  if (arow >= n) arow = n - 1;
  const ushort_t* aptr = A + (size_t)arow * (KK * 32) + (lane >> 4) * 8;

  f32x4 acc[8] = {};
#pragma unroll
  for (int kk = 0; kk < KK; ++kk) {
    short8v a = *(const short8v*)(aptr + kk * 32);
    const ushort_t* wp = Wp + ((size_t)(kk * 8) * 64 + lane) * 8;
#pragma unroll
    for (int j = 0; j < 8; ++j) {
      short8v b = *(const short8v*)(wp + (size_t)j * 512);
      acc[j] = __builtin_amdgcn_mfma_f32_16x16x32_bf16(a, b, acc[j], 0, 0, 0);
    }
  }
  int rbase = r0 + (lane >> 4) * 4;
  int colb = lane & 15;
  float bcol[8];
  if constexpr (ENC) {
#pragma unroll
    for (int j = 0; j < 8; ++j) bcol[j] = aux[j * 16 + colb];
  }
#pragma unroll
  for (int reg = 0; reg < 4; ++reg) {
    int row = rbase + reg;
    if (row < n) {
      if constexpr (ENC) {
#pragma unroll
        for (int j = 0; j < 8; ++j)
          C[(size_t)row * 128 + j * 16 + colb] = bf16_rte(fmaxf(acc[j][reg] + bcol[j], 0.f));
      } else {
        float s = aux[row];
#pragma unroll
        for (int j = 0; j < 8; ++j)
          C[(size_t)row * 128 + j * 16 + colb] = bf16_rte(acc[j][reg] * s);
      }
    }
  }
}

// ---------------- aggregation + bias + LayerNorm + ReLU (bf16 in/out) ----------------
// one wave per node; half-waves process even/odd edges; lane owns 4 channels (8B).

__global__ __launch_bounds__(256) void k_agg(const uint2* __restrict__ hw2,  // [n][32] (bf16x4)
                                             const int* __restrict__ rp,
                                             const int* __restrict__ csrc,
                                             const float* __restrict__ dis,
                                             const float* __restrict__ bias,
                                             const float* __restrict__ g,
                                             const float* __restrict__ bln,
                                             uint2* __restrict__ out2, int n) {
  int lane = threadIdx.x & 63;
  int half = lane >> 5;
  int cl = lane & 31;   // channels cl*4 .. cl*4+3
  int node = blockIdx.x * 4 + (threadIdx.x >> 6);
  if (node >= n) return;
  int start = rp[node], end = rp[node + 1];
  float a0 = 0.f, a1 = 0.f, a2 = 0.f, a3 = 0.f;
  int e = start + half;
  for (; e + 2 < end; e += 4) {   // this half handles e and e+2
    int s0 = csrc[e], s1 = csrc[e + 2];
    uint2 u0 = hw2[(size_t)s0 * 32 + cl];
    uint2 u1 = hw2[(size_t)s1 * 32 + cl];
    a0 += bf_lo(u0.x); a1 += bf_hi(u0.x); a2 += bf_lo(u0.y); a3 += bf_hi(u0.y);
    a0 += bf_lo(u1.x); a1 += bf_hi(u1.x); a2 += bf_lo(u1.y); a3 += bf_hi(u1.y);
  }
  if (e < end) {
    int s0 = csrc[e];
    uint2 u0 = hw2[(size_t)s0 * 32 + cl];
    a0 += bf_lo(u0.x); a1 += bf_hi(u0.x); a2 += bf_lo(u0.y); a3 += bf_hi(u0.y);
  }
  // combine even/odd halves
  a0 += __shfl_xor(a0, 32, 64);
  a1 += __shfl_xor(a1, 32, 64);
  a2 += __shfl_xor(a2, 32, 64);
  a3 += __shfl_xor(a3, 32, 64);
  // self loop (rows pre-scaled by dis[src]); then * dis[node] + bias
  uint2 us = hw2[(size_t)node * 32 + cl];
  a0 += bf_lo(us.x); a1 += bf_hi(us.x); a2 += bf_lo(us.y); a3 += bf_hi(us.y);
  float dn = dis[node];
  float4 bb = *(const float4*)&bias[cl * 4];
  a0 = fmaf(a0, dn, bb.x);
  a1 = fmaf(a1, dn, bb.y);
  a2 = fmaf(a2, dn, bb.z);
  a3 = fmaf(a3, dn, bb.w);
  // LayerNorm over 128 channels: reduce within each 32-lane half (each spans all channels)
  float s1v = a0 + a1 + a2 + a3;
  float s2v = a0 * a0 + a1 * a1 + a2 * a2 + a3 * a3;
#pragma unroll
  for (int m = 1; m < 32; m <<= 1) {
    s1v += __shfl_xor(s1v, m, 64);
    s2v += __shfl_xor(s2v, m, 64);
  }
  float mean = s1v * (1.0f / 128.0f);
  float var = s2v * (1.0f / 128.0f) - mean * mean;
  float rstd = rsqrtf(var + LN_EPS);
  float4 gg = *(const float4*)&g[cl * 4];
  float4 bl = *(const float4*)&bln[cl * 4];
  float y0 = fmaxf(fmaf((a0 - mean) * rstd, gg.x, bl.x), 0.f);
  float y1 = fmaxf(fmaf((a1 - mean) * rstd, gg.y, bl.y), 0.f);
  float y2 = fmaxf(fmaf((a2 - mean) * rstd, gg.z, bl.z), 0.f);
  float y3 = fmaxf(fmaf((a3 - mean) * rstd, gg.w, bl.w), 0.f);
  if (half == 0) {
    uint2 p;
    p.x = pack_bf16x2(y0, y1);
    p.y = pack_bf16x2(y2, y3);
    out2[(size_t)node * 32 + cl] = p;
  }
}

// ---------------- output head ----------------

__global__ __launch_bounds__(256) void k_out(const ushort_t* __restrict__ x1,
                                             const ushort_t* __restrict__ x2,
                                             const float* __restrict__ w,
                                             const float* __restrict__ b,
                                             float* __restrict__ out, int n) {
  __shared__ float wl[256 * 16];
  __shared__ float bl[16];
  int tid = threadIdx.x;
#pragma unroll
  for (int i = 0; i < 4; ++i) {
    int idx = (i * 256 + tid) * 4;
    *(float4*)&wl[idx] = *(const float4*)&w[idx];
  }
  if (tid < 16) bl[tid] = b[tid];
  __syncthreads();
  int node = blockIdx.x * 256 + tid;
  if (node >= n) return;
  float acc[16];
#pragma unroll
  for (int o = 0; o < 16; ++o) acc[o] = bl[o];

  const ushort_t* xr = x1 + (size_t)node * 128;
#pragma unroll 2
  for (int c = 0; c < 128; c += 8) {
    uint4 xv = *(const uint4*)&xr[c];
    float f0 = bf_lo(xv.x), f1 = bf_hi(xv.x), f2 = bf_lo(xv.y), f3 = bf_hi(xv.y);
    float f4 = bf_lo(xv.z), f5 = bf_hi(xv.z), f6 = bf_lo(xv.w), f7 = bf_hi(xv.w);
#pragma unroll
    for (int o = 0; o < 16; ++o) {
      acc[o] = fmaf(f0, wl[(c + 0) * 16 + o],
               fmaf(f1, wl[(c + 1) * 16 + o],
               fmaf(f2, wl[(c + 2) * 16 + o],
               fmaf(f3, wl[(c + 3) * 16 + o],
               fmaf(f4, wl[(c + 4) * 16 + o],
               fmaf(f5, wl[(c + 5) * 16 + o],
               fmaf(f6, wl[(c + 6) * 16 + o],
               fmaf(f7, wl[(c + 7) * 16 + o], acc[o]))))))));
    }
  }
  const ushort_t* xr2 = x2 + (size_t)node * 128;
#pragma unroll 2
  for (int c = 0; c < 128; c += 8) {
    uint4 xv = *(const uint4*)&xr2[c];
    float f0 = bf_lo(xv.x), f1 = bf_hi(xv.x), f2 = bf_lo(xv.y), f3 = bf_hi(xv.y);
    float f4 = bf_lo(xv.z), f5 = bf_hi(xv.z), f6 = bf_lo(xv.w), f7 = bf_hi(xv.w);
#pragma unroll
    for (int o = 0; o < 16; ++o) {
      acc[o] = fmaf(f0, wl[(128 + c + 0) * 16 + o],
               fmaf(f1, wl[(128 + c + 1) * 16 + o],
               fmaf(f2, wl[(128 + c + 2) * 16 + o],
               fmaf(f3, wl[(128 + c + 3) * 16 + o],
               fmaf(f4, wl[(128 + c + 4) * 16 + o],
               fmaf(f5, wl[(128 + c + 5) * 16 + o],
               fmaf(f6, wl[(128 + c + 6) * 16 + o],
               fmaf(f7, wl[(128 + c + 7) * 16 + o], acc[o]))))))));
    }
  }
#pragma unroll
  for (int o = 0; o < 4; ++o) {
    *(float4*)&out[(size_t)node * 16 + o * 4] =
        make_float4(acc[o * 4], acc[o * 4 + 1], acc[o * 4 + 2], acc[o * 4 + 3]);
  }
}

// ---------------- host ----------------

extern "C" void kernel_launch(void* const* d_in, const int* in_sizes, int n_in,
                              void* d_out, int out_size, void* d_ws, size_t ws_size,
                              hipStream_t stream) {
  const float* x = (const float*)d_in[0];
  const int* ei1 = (const int*)d_in[1];
  const int* ei2 = (const int*)d_in[2];
  const float* enc_w = (const float*)d_in[3];
  const float* enc_b = (const float*)d_in[4];
  const float* conv_w[3] = {(const float*)d_in[5], (const float*)d_in[9], (const float*)d_in[13]};
  const float* conv_b[3] = {(const float*)d_in[6], (const float*)d_in[10], (const float*)d_in[14]};
  const float* ln_g[3] = {(const float*)d_in[7], (const float*)d_in[11], (const float*)d_in[15]};
  const float* ln_b[3] = {(const float*)d_in[8], (const float*)d_in[12], (const float*)d_in[16]};
  const float* out_w = (const float*)d_in[17];
  const float* out_b = (const float*)d_in[18];
  float* out = (float*)d_out;

  const int N = NN;
  const int E = in_sizes[1] / 2;
  const int NB = (N + 255) >> 8;   // buckets of 256 nodes

  char* ws = (char*)d_ws;
  size_t off = 0;
  auto alloc = [&](size_t bytes) -> char* {
    char* p = ws + off;
    off += (bytes + 255) & ~(size_t)255;
    return p;
  };
  ushort_t* h0 = (ushort_t*)alloc((size_t)N * 128 * 2);   // encoder out (bf16)
  ushort_t* hb = (ushort_t*)alloc((size_t)N * 128 * 2);   // scaled gather buffer (bf16)
  ushort_t* p1 = (ushort_t*)alloc((size_t)N * 128 * 2);   // x1
  ushort_t* p2 = (ushort_t*)alloc((size_t)N * 128 * 2);   // x2
  ushort_t* xb = (ushort_t*)alloc((size_t)N * 64 * 2);    // x in bf16
  ushort_t* wpk[3];
  for (int l = 0; l < 3; ++l) wpk[l] = (ushort_t*)alloc(2048 * 8 * 2);
  ushort_t* wpe = (ushort_t*)alloc(1024 * 8 * 2);

  struct G {
    int* deg; int* fill; int* bfill; float* dis; int* rp; int* bsum;
    int* csrc; int2* pairs; const int* src; const int* dst;
  } g[2];
  for (int i = 0; i < 2; ++i) {
    g[i].deg = (int*)alloc((size_t)N * 4);
    g[i].fill = (int*)alloc((size_t)N * 4);
    g[i].bfill = (int*)alloc((size_t)NB * 4);
    g[i].dis = (float*)alloc((size_t)N * 4);
    g[i].rp = (int*)alloc((size_t)(N + 1) * 4);
    g[i].bsum = (int*)alloc(64 * 4);
    g[i].csrc = (int*)alloc((size_t)E * 4);
    g[i].pairs = (int2*)alloc((size_t)E * 8);
  }
  g[0].src = ei1; g[0].dst = ei1 + E;
  g[1].src = ei2; g[1].dst = ei2 + E;

  int nbScan = (N + 2047) / 2048;
  int ge = (E + 255) / 256;
  for (int i = 0; i < 2; ++i) {
    hipMemsetAsync(g[i].deg, 0, (size_t)N * 4, stream);
    hipMemsetAsync(g[i].fill, 0, (size_t)N * 4, stream);
    hipMemsetAsync(g[i].bfill, 0, (size_t)NB * 4, stream);
    k_hist<<<ge, 256, 0, stream>>>(g[i].dst, g[i].deg, E);
    k_dis<<<(N + 255) / 256, 256, 0, stream>>>(g[i].deg, g[i].dis, N);
    k_scanA<<<nbScan, 256, 0, stream>>>(g[i].deg, g[i].rp, g[i].bsum, N);
    k_scanB<<<1, 64, 0, stream>>>(g[i].bsum, nbScan);
    k_scanC<<<(N + 1 + 255) / 256, 256, 0, stream>>>(g[i].rp, g[i].bsum, N, E);
    k_bscatter<<<ge, 256, 0, stream>>>(g[i].src, g[i].dst, g[i].rp, g[i].bfill,
                                       g[i].pairs, E);
    k_fill2<<<ge, 256, 0, stream>>>(g[i].pairs, g[i].rp, g[i].fill, g[i].csrc, E);
  }

  // pack weights, convert x
  for (int l = 0; l < 3; ++l) k_packw<<<8, 256, 0, stream>>>(conv_w[l], wpk[l]);
  k_packw<<<4, 256, 0, stream>>>(enc_w, wpe);
  k_cvt<<<(N * 64 / 4 + 255) / 256, 256, 0, stream>>>(x, xb, N * 64 / 4);

  int gb = (N + 63) / 64;
  // shared encoder -> h0 (bf16 MFMA, relu+bias epilogue)
  k_gemm_mfma<2, true><<<gb, 256, 0, stream>>>(xb, wpe, enc_b, h0, N);

  // branch 1: h0 -> ... -> x1 in p1
  {
    const ushort_t* cur = h0;
    for (int l = 0; l < 3; ++l) {
      k_gemm_mfma<4, false><<<gb, 256, 0, stream>>>(cur, wpk[l], g[0].dis, hb, N);
      k_agg<<<(N + 3) / 4, 256, 0, stream>>>((const uint2*)hb, g[0].rp, g[0].csrc,
                                             g[0].dis, conv_b[l], ln_g[l], ln_b[l],
                                             (uint2*)p1, N);
      cur = p1;
    }
  }
  // branch 2: h0 -> ... -> x2 in p2
  {
    const ushort_t* cur = h0;
    for (int l = 0; l < 3; ++l) {
      k_gemm_mfma<4, false><<<gb, 256, 0, stream>>>(cur, wpk[l], g[1].dis, hb, N);
      k_agg<<<(N + 3) / 4, 256, 0, stream>>>((const uint2*)hb, g[1].rp, g[1].csrc,
                                             g[1].dis, conv_b[l], ln_g[l], ln_b[l],
                                             (uint2*)p2, N);
      cur = p2;
    }
  }

  k_out<<<(N + 255) / 256, 256, 0, stream>>>(p1, p2, out_w, out_b, out, N);
}